// Round 4
// baseline (3120.849 us; speedup 1.0000x reference)
//
#include <hip/hip_runtime.h>
#include <math.h>

#define PPT 2  // points per thread

typedef float f32x2 __attribute__((ext_vector_type(2)));
typedef float f32x4 __attribute__((ext_vector_type(4)));

// ---------------- featuremap repack: (4,H,W) -> (H,W,4) ----------------
__global__ void repack_fm_kernel(const float* __restrict__ fm,
                                 float4* __restrict__ out, int HW) {
    int idx = blockIdx.x * blockDim.x + threadIdx.x;
    if (idx >= HW) return;
    float4 v;
    v.x = fm[idx];
    v.y = fm[HW + idx];
    v.z = fm[2 * HW + idx];
    v.w = fm[3 * HW + idx];
    out[idx] = v;
}

// Exact GELU via Abramowitz-Stegun 7.1.26 erfc (|abs err| <= 1.5e-7), branchless.
// Phi(v) = 0.5*erfc(-v/sqrt(2)); for z=|v|/sqrt(2):
//   erfc(z) = (a1 t + a2 t^2 + a3 t^3 + a4 t^4 + a5 t^5) * exp(-z^2),  t=1/(1+p z)
__device__ __forceinline__ float gelu_exact(float v) {
    float z = fabsf(v) * 0.70710678118654752440f;
    float t = __builtin_amdgcn_rcpf(fmaf(0.3275911f, z, 1.0f));
    float e = __expf(-z * z);
    float p = fmaf(1.061405429f, t, -1.453152027f);
    p = fmaf(p, t, 1.421413741f);
    p = fmaf(p, t, -0.284496736f);
    p = fmaf(p, t, 0.254829592f);
    p = p * t;                       // erfc(z) * exp(z^2)
    float he = 0.5f * p * e;         // 0.5 * erfc(|v|/sqrt2)
    float phi = (v >= 0.0f) ? (1.0f - he) : he;
    return v * phi;
}

// LDS weight layout offsets (floats)
#define OFF_W1 0
#define OFF_B1 128
#define OFF_W2 144
#define OFF_B2 400
#define OFF_W3 416
#define OFF_B3 672
#define OFF_WH 688
#define OFF_BH 736
#define NW_TOTAL 739

template <bool REPACKED>
__global__ __launch_bounds__(256)
__attribute__((amdgpu_waves_per_eu(5, 5)))
void fused_mlp_kernel(
    const float* __restrict__ x,
    const float* __restrict__ fm,    // original (4,H,W), used if !REPACKED
    const float4* __restrict__ fmr,  // repacked (H,W,4), used if REPACKED
    const float* __restrict__ W1, const float* __restrict__ b1,
    const float* __restrict__ W2, const float* __restrict__ b2,
    const float* __restrict__ W3, const float* __restrict__ b3,
    const float* __restrict__ Wh, const float* __restrict__ bh,
    float* __restrict__ out, int B, int H, int W)
{
    __shared__ float wl[NW_TOTAL];
    {
        int t = threadIdx.x;
        if (t < 128) wl[OFF_W1 + t] = W1[t];
        if (t < 16)  wl[OFF_B1 + t] = b1[t];
        wl[OFF_W2 + t] = W2[t];          // 256 threads, 256 elems
        if (t < 16)  wl[OFF_B2 + t] = b2[t];
        wl[OFF_W3 + t] = W3[t];
        if (t < 16)  wl[OFF_B3 + t] = b3[t];
        if (t < 48)  wl[OFF_WH + t] = Wh[t];
        if (t < 3)   wl[OFF_BH + t] = bh[t];
    }
    __syncthreads();

    int tid = blockIdx.x * blockDim.x + threadIdx.x;
    int base = tid * PPT;
    if (base >= B) return;
    int np = B - base;
    if (np > PPT) np = PPT;

    // ---- load x, 3 floats per point (streaming -> nontemporal) ----
    float xin[PPT][3];
    if (np == PPT) {
        const f32x2* xp = (const f32x2*)(x + (size_t)base * 3);
        f32x2 a = __builtin_nontemporal_load(xp + 0);
        f32x2 b = __builtin_nontemporal_load(xp + 1);
        f32x2 c = __builtin_nontemporal_load(xp + 2);
        xin[0][0] = a.x; xin[0][1] = a.y; xin[0][2] = b.x;
        xin[1][0] = b.y; xin[1][1] = c.x; xin[1][2] = c.y;
    } else {
        #pragma unroll
        for (int p = 0; p < PPT; ++p) {
            int i = base + p; if (i > B - 1) i = B - 1;
            xin[p][0] = x[(size_t)i * 3 + 0];
            xin[p][1] = x[(size_t)i * 3 + 1];
            xin[p][2] = x[(size_t)i * 3 + 2];
        }
    }

    // ---- bilinear sample (border padding, align_corners=False) + build inp ----
    float inp[PPT][8];
    #pragma unroll
    for (int p = 0; p < PPT; ++p) {
        float gx = xin[p][0] * 2.0f - 1.0f;
        float gy = xin[p][1] * 2.0f - 1.0f;
        float ix = ((gx + 1.0f) * (float)W - 1.0f) * 0.5f;
        float iy = ((gy + 1.0f) * (float)H - 1.0f) * 0.5f;
        ix = fminf(fmaxf(ix, 0.0f), (float)(W - 1));
        iy = fminf(fmaxf(iy, 0.0f), (float)(H - 1));
        float x0f = floorf(ix), y0f = floorf(iy);
        float wx = ix - x0f, wy = iy - y0f;
        int x0 = (int)x0f, y0 = (int)y0f;
        int x1 = x0 + 1; if (x1 > W - 1) x1 = W - 1;
        int y1 = y0 + 1; if (y1 > H - 1) y1 = H - 1;

        float4 f00, f01, f10, f11;
        if (REPACKED) {
            f00 = fmr[y0 * W + x0];
            f01 = fmr[y0 * W + x1];
            f10 = fmr[y1 * W + x0];
            f11 = fmr[y1 * W + x1];
        } else {
            int HW = H * W;
            const float* c0 = fm;
            const float* c1 = fm + HW;
            const float* c2 = fm + 2 * HW;
            const float* c3 = fm + 3 * HW;
            int i00 = y0 * W + x0, i01 = y0 * W + x1;
            int i10 = y1 * W + x0, i11 = y1 * W + x1;
            f00 = make_float4(c0[i00], c1[i00], c2[i00], c3[i00]);
            f01 = make_float4(c0[i01], c1[i01], c2[i01], c3[i01]);
            f10 = make_float4(c0[i10], c1[i10], c2[i10], c3[i10]);
            f11 = make_float4(c0[i11], c1[i11], c2[i11], c3[i11]);
        }
        float omwx = 1.0f - wx, omwy = 1.0f - wy;
        float tx = f00.x * omwx + f01.x * wx, bx = f10.x * omwx + f11.x * wx;
        float ty = f00.y * omwx + f01.y * wx, by = f10.y * omwx + f11.y * wx;
        float tz = f00.z * omwx + f01.z * wx, bz = f10.z * omwx + f11.z * wx;
        float tw = f00.w * omwx + f01.w * wx, bw = f10.w * omwx + f11.w * wx;

        inp[p][0] = xin[p][0];
        inp[p][1] = xin[p][1];
        inp[p][2] = xin[p][2];
        inp[p][3] = tx * omwy + bx * wy;
        inp[p][4] = ty * omwy + by * wy;
        inp[p][5] = tz * omwy + bz * wy;
        inp[p][6] = tw * omwy + bw * wy;
        inp[p][7] = __expf(xin[p][2]) - 1.0f;   // expm1, |x|<=1 so no cancellation issue
    }

    // ---- layer 1: 8 -> 16, exact gelu ----
    float h1[PPT][16];
    #pragma unroll
    for (int j = 0; j < 16; ++j) {
        float acc[PPT];
        #pragma unroll
        for (int p = 0; p < PPT; ++p) acc[p] = wl[OFF_B1 + j];
        #pragma unroll
        for (int k = 0; k < 8; ++k) {
            float w = wl[OFF_W1 + j * 8 + k];
            #pragma unroll
            for (int p = 0; p < PPT; ++p) acc[p] = fmaf(w, inp[p][k], acc[p]);
        }
        #pragma unroll
        for (int p = 0; p < PPT; ++p) h1[p][j] = gelu_exact(acc[p]);
    }

    // ---- layer 2: 16 -> 16 ----
    float h2[PPT][16];
    #pragma unroll
    for (int j = 0; j < 16; ++j) {
        float acc[PPT];
        #pragma unroll
        for (int p = 0; p < PPT; ++p) acc[p] = wl[OFF_B2 + j];
        #pragma unroll
        for (int k = 0; k < 16; ++k) {
            float w = wl[OFF_W2 + j * 16 + k];
            #pragma unroll
            for (int p = 0; p < PPT; ++p) acc[p] = fmaf(w, h1[p][k], acc[p]);
        }
        #pragma unroll
        for (int p = 0; p < PPT; ++p) h2[p][j] = gelu_exact(acc[p]);
    }

    // ---- layer 3: 16 -> 16 ----
    float h3[PPT][16];
    #pragma unroll
    for (int j = 0; j < 16; ++j) {
        float acc[PPT];
        #pragma unroll
        for (int p = 0; p < PPT; ++p) acc[p] = wl[OFF_B3 + j];
        #pragma unroll
        for (int k = 0; k < 16; ++k) {
            float w = wl[OFF_W3 + j * 16 + k];
            #pragma unroll
            for (int p = 0; p < PPT; ++p) acc[p] = fmaf(w, h2[p][k], acc[p]);
        }
        #pragma unroll
        for (int p = 0; p < PPT; ++p) h3[p][j] = gelu_exact(acc[p]);
    }

    // ---- head: 16 -> 3 ----
    float o[PPT][3];
    #pragma unroll
    for (int c = 0; c < 3; ++c) {
        float acc[PPT];
        #pragma unroll
        for (int p = 0; p < PPT; ++p) acc[p] = wl[OFF_BH + c];
        #pragma unroll
        for (int k = 0; k < 16; ++k) {
            float w = wl[OFF_WH + c * 16 + k];
            #pragma unroll
            for (int p = 0; p < PPT; ++p) acc[p] = fmaf(w, h3[p][k], acc[p]);
        }
        #pragma unroll
        for (int p = 0; p < PPT; ++p) o[p][c] = acc[p];
    }

    // ---- store (streaming -> nontemporal) ----
    if (np == PPT) {
        f32x2* op = (f32x2*)(out + (size_t)base * 3);
        f32x2 s0; s0.x = o[0][0]; s0.y = o[0][1];
        f32x2 s1; s1.x = o[0][2]; s1.y = o[1][0];
        f32x2 s2; s2.x = o[1][1]; s2.y = o[1][2];
        __builtin_nontemporal_store(s0, op + 0);
        __builtin_nontemporal_store(s1, op + 1);
        __builtin_nontemporal_store(s2, op + 2);
    } else {
        #pragma unroll
        for (int p = 0; p < PPT; ++p) {
            if (p < np) {
                out[(size_t)(base + p) * 3 + 0] = o[p][0];
                out[(size_t)(base + p) * 3 + 1] = o[p][1];
                out[(size_t)(base + p) * 3 + 2] = o[p][2];
            }
        }
    }
}

extern "C" void kernel_launch(void* const* d_in, const int* in_sizes, int n_in,
                              void* d_out, int out_size, void* d_ws, size_t ws_size,
                              hipStream_t stream) {
    const float* x  = (const float*)d_in[0];
    const float* fm = (const float*)d_in[1];
    const float* W1 = (const float*)d_in[2];
    const float* b1 = (const float*)d_in[3];
    const float* W2 = (const float*)d_in[4];
    const float* b2 = (const float*)d_in[5];
    const float* W3 = (const float*)d_in[6];
    const float* b3 = (const float*)d_in[7];
    const float* Wh = (const float*)d_in[8];
    const float* bh = (const float*)d_in[9];
    float* out = (float*)d_out;

    int B  = in_sizes[0] / 3;
    int HW = in_sizes[1] / 4;
    // assume square map (reference: 1024x1024)
    int H = 1;
    while ((long long)(H + 1) * (H + 1) <= (long long)HW) ++H;  // integer sqrt
    int W = HW / H;

    bool repack = (ws_size >= (size_t)HW * sizeof(float4));

    if (repack) {
        int blocks = (HW + 255) / 256;
        repack_fm_kernel<<<blocks, 256, 0, stream>>>(fm, (float4*)d_ws, HW);
    }

    int threads_needed = (B + PPT - 1) / PPT;
    int blocks = (threads_needed + 255) / 256;
    if (repack) {
        fused_mlp_kernel<true><<<blocks, 256, 0, stream>>>(
            x, fm, (const float4*)d_ws, W1, b1, W2, b2, W3, b3, Wh, bh,
            out, B, H, W);
    } else {
        fused_mlp_kernel<false><<<blocks, 256, 0, stream>>>(
            x, fm, (const float4*)d_ws, W1, b1, W2, b2, W3, b3, Wh, bh,
            out, B, H, W);
    }
}

// Round 5
// 225.563 us; speedup vs baseline: 13.8358x; 13.8358x over previous
//
#include <hip/hip_runtime.h>
#include <math.h>

typedef float f32x4 __attribute__((ext_vector_type(4)));

// ---------------- featuremap repack: (4,H,W) -> (H,W,4) ----------------
__global__ void repack_fm_kernel(const float* __restrict__ fm,
                                 float4* __restrict__ out, int HW) {
    int idx = blockIdx.x * blockDim.x + threadIdx.x;
    if (idx >= HW) return;
    float4 v;
    v.x = fm[idx];
    v.y = fm[HW + idx];
    v.z = fm[2 * HW + idx];
    v.w = fm[3 * HW + idx];
    out[idx] = v;
}

// Exact GELU via Abramowitz-Stegun 7.1.26 erfc (|abs err| <= 1.5e-7), branchless.
__device__ __forceinline__ float gelu_exact(float v) {
    float z = fabsf(v) * 0.70710678118654752440f;
    float t = __builtin_amdgcn_rcpf(fmaf(0.3275911f, z, 1.0f));
    float e = __expf(-z * z);
    float p = fmaf(1.061405429f, t, -1.453152027f);
    p = fmaf(p, t, 1.421413741f);
    p = fmaf(p, t, -0.284496736f);
    p = fmaf(p, t, 0.254829592f);
    p = p * t;                       // erfc(z) * exp(z^2)
    float he = 0.5f * p * e;         // 0.5 * erfc(|v|/sqrt2)
    float phi = (v >= 0.0f) ? (1.0f - he) : he;
    return v * phi;
}

// LDS weight layout offsets (floats; all float4-aligned)
#define OFF_W1 0
#define OFF_B1 128
#define OFF_W2 144
#define OFF_B2 400
#define OFF_W3 416
#define OFF_B3 672
#define OFF_WH 688
#define OFF_BH 736
#define NW_TOTAL 740

__device__ __forceinline__ float dot4(f32x4 w, const float* h) {
    float a = fmaf(w.x, h[0], 0.0f);
    a = fmaf(w.y, h[1], a);
    a = fmaf(w.z, h[2], a);
    a = fmaf(w.w, h[3], a);
    return a;
}

template <bool REPACKED>
__global__ __launch_bounds__(256) void fused_mlp_kernel(
    const float* __restrict__ x,
    const float* __restrict__ fm,    // original (4,H,W), used if !REPACKED
    const float4* __restrict__ fmr,  // repacked (H,W,4), used if REPACKED
    const float* __restrict__ W1, const float* __restrict__ b1,
    const float* __restrict__ W2, const float* __restrict__ b2,
    const float* __restrict__ W3, const float* __restrict__ b3,
    const float* __restrict__ Wh, const float* __restrict__ bh,
    float* __restrict__ out, int B, int H, int W)
{
    __shared__ __align__(16) float wl[NW_TOTAL];
    {
        int t = threadIdx.x;
        if (t < 128) wl[OFF_W1 + t] = W1[t];
        if (t < 16)  wl[OFF_B1 + t] = b1[t];
        wl[OFF_W2 + t] = W2[t];          // 256 threads, 256 elems
        if (t < 16)  wl[OFF_B2 + t] = b2[t];
        wl[OFF_W3 + t] = W3[t];
        if (t < 16)  wl[OFF_B3 + t] = b3[t];
        if (t < 48)  wl[OFF_WH + t] = Wh[t];
        if (t < 3)   wl[OFF_BH + t] = bh[t];
    }
    __syncthreads();

    int i = blockIdx.x * blockDim.x + threadIdx.x;
    if (i >= B) return;

    // ---- load x (3 floats, streaming) ----
    const float* xp = x + (size_t)i * 3;
    float xa = __builtin_nontemporal_load(xp + 0);
    float xb = __builtin_nontemporal_load(xp + 1);
    float xc = __builtin_nontemporal_load(xp + 2);

    // ---- bilinear sample (border padding, align_corners=False) ----
    float inp[8];
    {
        float gx = xa * 2.0f - 1.0f;
        float gy = xb * 2.0f - 1.0f;
        float ix = ((gx + 1.0f) * (float)W - 1.0f) * 0.5f;
        float iy = ((gy + 1.0f) * (float)H - 1.0f) * 0.5f;
        ix = fminf(fmaxf(ix, 0.0f), (float)(W - 1));
        iy = fminf(fmaxf(iy, 0.0f), (float)(H - 1));
        float x0f = floorf(ix), y0f = floorf(iy);
        float wx = ix - x0f, wy = iy - y0f;
        int x0 = (int)x0f, y0 = (int)y0f;
        int x1 = x0 + 1; if (x1 > W - 1) x1 = W - 1;
        int y1 = y0 + 1; if (y1 > H - 1) y1 = H - 1;

        float4 f00, f01, f10, f11;
        if (REPACKED) {
            f00 = fmr[y0 * W + x0];
            f01 = fmr[y0 * W + x1];
            f10 = fmr[y1 * W + x0];
            f11 = fmr[y1 * W + x1];
        } else {
            int HW = H * W;
            const float* c0 = fm;
            const float* c1 = fm + HW;
            const float* c2 = fm + 2 * HW;
            const float* c3 = fm + 3 * HW;
            int i00 = y0 * W + x0, i01 = y0 * W + x1;
            int i10 = y1 * W + x0, i11 = y1 * W + x1;
            f00 = make_float4(c0[i00], c1[i00], c2[i00], c3[i00]);
            f01 = make_float4(c0[i01], c1[i01], c2[i01], c3[i01]);
            f10 = make_float4(c0[i10], c1[i10], c2[i10], c3[i10]);
            f11 = make_float4(c0[i11], c1[i11], c2[i11], c3[i11]);
        }
        float omwx = 1.0f - wx, omwy = 1.0f - wy;
        float tx = f00.x * omwx + f01.x * wx, bx = f10.x * omwx + f11.x * wx;
        float ty = f00.y * omwx + f01.y * wx, by = f10.y * omwx + f11.y * wx;
        float tz = f00.z * omwx + f01.z * wx, bz = f10.z * omwx + f11.z * wx;
        float tw = f00.w * omwx + f01.w * wx, bw = f10.w * omwx + f11.w * wx;

        inp[0] = xa;
        inp[1] = xb;
        inp[2] = xc;
        inp[3] = tx * omwy + bx * wy;
        inp[4] = ty * omwy + by * wy;
        inp[5] = tz * omwy + bz * wy;
        inp[6] = tw * omwy + bw * wy;
        inp[7] = __expf(xc) - 1.0f;   // expm1, |x|<=1: no cancellation issue
    }

    // ---- layer 1: 8 -> 16, exact gelu ----
    float h1[16];
    #pragma unroll
    for (int j = 0; j < 16; ++j) {
        f32x4 w0 = *(const f32x4*)&wl[OFF_W1 + j * 8 + 0];
        f32x4 w1 = *(const f32x4*)&wl[OFF_W1 + j * 8 + 4];
        float acc = wl[OFF_B1 + j] + dot4(w0, &inp[0]) + dot4(w1, &inp[4]);
        h1[j] = gelu_exact(acc);
    }

    // ---- layer 2: 16 -> 16 ----
    float h2[16];
    #pragma unroll
    for (int j = 0; j < 16; ++j) {
        f32x4 w0 = *(const f32x4*)&wl[OFF_W2 + j * 16 + 0];
        f32x4 w1 = *(const f32x4*)&wl[OFF_W2 + j * 16 + 4];
        f32x4 w2 = *(const f32x4*)&wl[OFF_W2 + j * 16 + 8];
        f32x4 w3 = *(const f32x4*)&wl[OFF_W2 + j * 16 + 12];
        float acc = wl[OFF_B2 + j] + dot4(w0, &h1[0]) + dot4(w1, &h1[4])
                  + dot4(w2, &h1[8]) + dot4(w3, &h1[12]);
        h2[j] = gelu_exact(acc);
    }

    // ---- layer 3: 16 -> 16 ----
    float h3[16];
    #pragma unroll
    for (int j = 0; j < 16; ++j) {
        f32x4 w0 = *(const f32x4*)&wl[OFF_W3 + j * 16 + 0];
        f32x4 w1 = *(const f32x4*)&wl[OFF_W3 + j * 16 + 4];
        f32x4 w2 = *(const f32x4*)&wl[OFF_W3 + j * 16 + 8];
        f32x4 w3 = *(const f32x4*)&wl[OFF_W3 + j * 16 + 12];
        float acc = wl[OFF_B3 + j] + dot4(w0, &h2[0]) + dot4(w1, &h2[4])
                  + dot4(w2, &h2[8]) + dot4(w3, &h2[12]);
        h3[j] = gelu_exact(acc);
    }

    // ---- head: 16 -> 3 + store (streaming) ----
    float* op = out + (size_t)i * 3;
    #pragma unroll
    for (int c = 0; c < 3; ++c) {
        f32x4 w0 = *(const f32x4*)&wl[OFF_WH + c * 16 + 0];
        f32x4 w1 = *(const f32x4*)&wl[OFF_WH + c * 16 + 4];
        f32x4 w2 = *(const f32x4*)&wl[OFF_WH + c * 16 + 8];
        f32x4 w3 = *(const f32x4*)&wl[OFF_WH + c * 16 + 12];
        float acc = wl[OFF_BH + c] + dot4(w0, &h3[0]) + dot4(w1, &h3[4])
                  + dot4(w2, &h3[8]) + dot4(w3, &h3[12]);
        __builtin_nontemporal_store(acc, op + c);
    }
}

extern "C" void kernel_launch(void* const* d_in, const int* in_sizes, int n_in,
                              void* d_out, int out_size, void* d_ws, size_t ws_size,
                              hipStream_t stream) {
    const float* x  = (const float*)d_in[0];
    const float* fm = (const float*)d_in[1];
    const float* W1 = (const float*)d_in[2];
    const float* b1 = (const float*)d_in[3];
    const float* W2 = (const float*)d_in[4];
    const float* b2 = (const float*)d_in[5];
    const float* W3 = (const float*)d_in[6];
    const float* b3 = (const float*)d_in[7];
    const float* Wh = (const float*)d_in[8];
    const float* bh = (const float*)d_in[9];
    float* out = (float*)d_out;

    int B  = in_sizes[0] / 3;
    int HW = in_sizes[1] / 4;
    // assume square map (reference: 1024x1024)
    int H = 1;
    while ((long long)(H + 1) * (H + 1) <= (long long)HW) ++H;  // integer sqrt
    int W = HW / H;

    bool repack = (ws_size >= (size_t)HW * sizeof(float4));

    if (repack) {
        int blocks = (HW + 255) / 256;
        repack_fm_kernel<<<blocks, 256, 0, stream>>>(fm, (float4*)d_ws, HW);
    }

    int blocks = (B + 255) / 256;
    if (repack) {
        fused_mlp_kernel<true><<<blocks, 256, 0, stream>>>(
            x, fm, (const float4*)d_ws, W1, b1, W2, b2, W3, b3, Wh, bh,
            out, B, H, W);
    } else {
        fused_mlp_kernel<false><<<blocks, 256, 0, stream>>>(
            x, fm, (const float4*)d_ws, W1, b1, W2, b2, W3, b3, Wh, bh,
            out, B, H, W);
    }
}

// Round 6
// 167.389 us; speedup vs baseline: 18.6442x; 1.3475x over previous
//
#include <hip/hip_runtime.h>
#include <math.h>

typedef float f32x4 __attribute__((ext_vector_type(4)));

// ---------------- featuremap repack: (4,H,W) -> (H,W,4) ----------------
__global__ void repack_fm_kernel(const float* __restrict__ fm,
                                 float4* __restrict__ out, int HW) {
    int idx = blockIdx.x * blockDim.x + threadIdx.x;
    if (idx >= HW) return;
    float4 v;
    v.x = fm[idx];
    v.y = fm[HW + idx];
    v.z = fm[2 * HW + idx];
    v.w = fm[3 * HW + idx];
    out[idx] = v;
}

// Exact GELU via Abramowitz-Stegun 7.1.26 erfc (|abs err| <= 1.5e-7), branchless.
__device__ __forceinline__ float gelu_exact(float v) {
    float z = fabsf(v) * 0.70710678118654752440f;
    float t = __builtin_amdgcn_rcpf(fmaf(0.3275911f, z, 1.0f));
    float e = __expf(-z * z);
    float p = fmaf(1.061405429f, t, -1.453152027f);
    p = fmaf(p, t, 1.421413741f);
    p = fmaf(p, t, -0.284496736f);
    p = fmaf(p, t, 0.254829592f);
    p = p * t;                       // erfc(z) * exp(z^2)
    float he = 0.5f * p * e;         // 0.5 * erfc(|v|/sqrt2)
    float phi = (v >= 0.0f) ? (1.0f - he) : he;
    return v * phi;
}

// Weights read DIRECTLY from global with wave-uniform (compile-time) offsets:
// the compiler scalarizes these to s_load -> SGPRs (scalar cache), so the
// vector memory and LDS pipes carry zero weight traffic. Each v_fma uses the
// weight as its single SGPR source operand.
template <bool REPACKED>
__global__ __launch_bounds__(256) void fused_mlp_kernel(
    const float* __restrict__ x,
    const float* __restrict__ fm,    // original (4,H,W), used if !REPACKED
    const float4* __restrict__ fmr,  // repacked (H,W,4), used if REPACKED
    const float* __restrict__ W1, const float* __restrict__ b1,
    const float* __restrict__ W2, const float* __restrict__ b2,
    const float* __restrict__ W3, const float* __restrict__ b3,
    const float* __restrict__ Wh, const float* __restrict__ bh,
    float* __restrict__ out, int B, int H, int W)
{
    int i = blockIdx.x * blockDim.x + threadIdx.x;
    if (i >= B) return;   // B is a multiple of 256 in practice -> wave-uniform

    // ---- load x (3 floats, streaming) ----
    const float* xp = x + (size_t)i * 3;
    float xa = __builtin_nontemporal_load(xp + 0);
    float xb = __builtin_nontemporal_load(xp + 1);
    float xc = __builtin_nontemporal_load(xp + 2);

    // ---- bilinear sample (border padding, align_corners=False) ----
    float inp[8];
    {
        float gx = xa * 2.0f - 1.0f;
        float gy = xb * 2.0f - 1.0f;
        float ix = ((gx + 1.0f) * (float)W - 1.0f) * 0.5f;
        float iy = ((gy + 1.0f) * (float)H - 1.0f) * 0.5f;
        ix = fminf(fmaxf(ix, 0.0f), (float)(W - 1));
        iy = fminf(fmaxf(iy, 0.0f), (float)(H - 1));
        float x0f = floorf(ix), y0f = floorf(iy);
        float wx = ix - x0f, wy = iy - y0f;
        int x0 = (int)x0f, y0 = (int)y0f;
        int x1 = x0 + 1; if (x1 > W - 1) x1 = W - 1;
        int y1 = y0 + 1; if (y1 > H - 1) y1 = H - 1;

        float4 f00, f01, f10, f11;
        if (REPACKED) {
            f00 = fmr[y0 * W + x0];
            f01 = fmr[y0 * W + x1];
            f10 = fmr[y1 * W + x0];
            f11 = fmr[y1 * W + x1];
        } else {
            int HW = H * W;
            const float* c0 = fm;
            const float* c1 = fm + HW;
            const float* c2 = fm + 2 * HW;
            const float* c3 = fm + 3 * HW;
            int i00 = y0 * W + x0, i01 = y0 * W + x1;
            int i10 = y1 * W + x0, i11 = y1 * W + x1;
            f00 = make_float4(c0[i00], c1[i00], c2[i00], c3[i00]);
            f01 = make_float4(c0[i01], c1[i01], c2[i01], c3[i01]);
            f10 = make_float4(c0[i10], c1[i10], c2[i10], c3[i10]);
            f11 = make_float4(c0[i11], c1[i11], c2[i11], c3[i11]);
        }
        float omwx = 1.0f - wx, omwy = 1.0f - wy;
        float tx = f00.x * omwx + f01.x * wx, bx = f10.x * omwx + f11.x * wx;
        float ty = f00.y * omwx + f01.y * wx, by = f10.y * omwx + f11.y * wx;
        float tz = f00.z * omwx + f01.z * wx, bz = f10.z * omwx + f11.z * wx;
        float tw = f00.w * omwx + f01.w * wx, bw = f10.w * omwx + f11.w * wx;

        inp[0] = xa;
        inp[1] = xb;
        inp[2] = xc;
        inp[3] = tx * omwy + bx * wy;
        inp[4] = ty * omwy + by * wy;
        inp[5] = tz * omwy + bz * wy;
        inp[6] = tw * omwy + bw * wy;
        inp[7] = __expf(xc) - 1.0f;   // expm1, |x|<=1: no cancellation issue
    }

    // ---- layer 1: 8 -> 16, exact gelu ----
    float h1[16];
    #pragma unroll
    for (int j = 0; j < 16; ++j) {
        float acc = b1[j];
        #pragma unroll
        for (int k = 0; k < 8; ++k)
            acc = fmaf(W1[j * 8 + k], inp[k], acc);
        h1[j] = gelu_exact(acc);
    }

    // ---- layer 2: 16 -> 16 ----
    float h2[16];
    #pragma unroll
    for (int j = 0; j < 16; ++j) {
        float acc = b2[j];
        #pragma unroll
        for (int k = 0; k < 16; ++k)
            acc = fmaf(W2[j * 16 + k], h1[k], acc);
        h2[j] = gelu_exact(acc);
    }

    // ---- layer 3: 16 -> 16 ----
    float h3[16];
    #pragma unroll
    for (int j = 0; j < 16; ++j) {
        float acc = b3[j];
        #pragma unroll
        for (int k = 0; k < 16; ++k)
            acc = fmaf(W3[j * 16 + k], h2[k], acc);
        h3[j] = gelu_exact(acc);
    }

    // ---- head: 16 -> 3 + store (streaming) ----
    float* op = out + (size_t)i * 3;
    #pragma unroll
    for (int c = 0; c < 3; ++c) {
        float acc = bh[c];
        #pragma unroll
        for (int k = 0; k < 16; ++k)
            acc = fmaf(Wh[c * 16 + k], h3[k], acc);
        __builtin_nontemporal_store(acc, op + c);
    }
}

extern "C" void kernel_launch(void* const* d_in, const int* in_sizes, int n_in,
                              void* d_out, int out_size, void* d_ws, size_t ws_size,
                              hipStream_t stream) {
    const float* x  = (const float*)d_in[0];
    const float* fm = (const float*)d_in[1];
    const float* W1 = (const float*)d_in[2];
    const float* b1 = (const float*)d_in[3];
    const float* W2 = (const float*)d_in[4];
    const float* b2 = (const float*)d_in[5];
    const float* W3 = (const float*)d_in[6];
    const float* b3 = (const float*)d_in[7];
    const float* Wh = (const float*)d_in[8];
    const float* bh = (const float*)d_in[9];
    float* out = (float*)d_out;

    int B  = in_sizes[0] / 3;
    int HW = in_sizes[1] / 4;
    // assume square map (reference: 1024x1024)
    int H = 1;
    while ((long long)(H + 1) * (H + 1) <= (long long)HW) ++H;  // integer sqrt
    int W = HW / H;

    bool repack = (ws_size >= (size_t)HW * sizeof(float4));

    if (repack) {
        int blocks = (HW + 255) / 256;
        repack_fm_kernel<<<blocks, 256, 0, stream>>>(fm, (float4*)d_ws, HW);
    }

    int blocks = (B + 255) / 256;
    if (repack) {
        fused_mlp_kernel<true><<<blocks, 256, 0, stream>>>(
            x, fm, (const float4*)d_ws, W1, b1, W2, b2, W3, b3, Wh, bh,
            out, B, H, W);
    } else {
        fused_mlp_kernel<false><<<blocks, 256, 0, stream>>>(
            x, fm, (const float4*)d_ws, W1, b1, W2, b2, W3, b3, Wh, bh,
            out, B, H, W);
    }
}

// Round 7
// 159.123 us; speedup vs baseline: 19.6128x; 1.0520x over previous
//
#include <hip/hip_runtime.h>
#include <math.h>

typedef float f32x4 __attribute__((ext_vector_type(4)));

#define GT_N 1024
#define GT_SCALE 102.3f          // 1/delta, delta = 10/1023
#define GT_DELTA (10.0f / 1023.0f)

// ---------------- featuremap repack: (4,H,W) -> (H,W,4) ----------------
__global__ void repack_fm_kernel(const float* __restrict__ fm,
                                 float4* __restrict__ out, int HW) {
    int idx = blockIdx.x * blockDim.x + threadIdx.x;
    if (idx >= HW) return;
    float4 v;
    v.x = fm[idx];
    v.y = fm[HW + idx];
    v.z = fm[2 * HW + idx];
    v.w = fm[3 * HW + idx];
    out[idx] = v;
}

// ---------------- exact-GELU table: 1024 x {g, dg} over [-5,5] ----------------
__global__ void build_gelu_table_kernel(float2* __restrict__ tbl) {
    int i = blockIdx.x * blockDim.x + threadIdx.x;
    if (i >= GT_N) return;
    float v0 = -5.0f + (float)i * GT_DELTA;
    float v1 = v0 + GT_DELTA;
    float g0 = 0.5f * v0 * (1.0f + erff(v0 * 0.70710678118654752440f));
    float g1 = 0.5f * v1 * (1.0f + erff(v1 * 0.70710678118654752440f));
    float2 e; e.x = g0; e.y = g1 - g0;
    tbl[i] = e;
}

// Fallback exact GELU (A&S 7.1.26 erfc), branchless — used only if ws too small.
__device__ __forceinline__ float gelu_as(float v) {
    float z = fabsf(v) * 0.70710678118654752440f;
    float t = __builtin_amdgcn_rcpf(fmaf(0.3275911f, z, 1.0f));
    float e = __expf(-z * z);
    float p = fmaf(1.061405429f, t, -1.453152027f);
    p = fmaf(p, t, 1.421413741f);
    p = fmaf(p, t, -0.284496736f);
    p = fmaf(p, t, 0.254829592f);
    p = p * t;
    float he = 0.5f * p * e;
    float phi = (v >= 0.0f) ? (1.0f - he) : he;
    return v * phi;
}

__device__ __forceinline__ float gelu_tbl(float v, const float2* __restrict__ gt) {
    float u = fminf(fmaxf(v, -5.0f), 5.0f);
    float t = (u + 5.0f) * GT_SCALE;       // in [0, 1023.00004]
    float fi = floorf(t);
    int idx = (int)fi;
    float f = t - fi;
    float2 e = gt[idx];
    float g = fmaf(f, e.y, e.x);
    return (v > 5.0f) ? v : g;             // v>5: gelu(v)==v to <2e-6
}

// Weights read directly from global with wave-uniform (compile-time) offsets ->
// compiler scalarizes to s_load/SGPR (scalar cache). Zero LDS/VMEM weight traffic.
template <bool REPACKED, bool TABLE>
__global__ __launch_bounds__(256) void fused_mlp_kernel(
    const float* __restrict__ x,
    const float* __restrict__ fm,    // original (4,H,W), used if !REPACKED
    const float4* __restrict__ fmr,  // repacked (H,W,4), used if REPACKED
    const float2* __restrict__ gtab, // global gelu table, used if TABLE
    const float* __restrict__ W1, const float* __restrict__ b1,
    const float* __restrict__ W2, const float* __restrict__ b2,
    const float* __restrict__ W3, const float* __restrict__ b3,
    const float* __restrict__ Wh, const float* __restrict__ bh,
    float* __restrict__ out, int B, int H, int W)
{
    __shared__ float2 gt[GT_N];
    if (TABLE) {
        int t = threadIdx.x;
        #pragma unroll
        for (int k = 0; k < GT_N / 256; ++k)
            gt[t + 256 * k] = gtab[t + 256 * k];
        __syncthreads();
    }

    int i = blockIdx.x * blockDim.x + threadIdx.x;
    if (i >= B) return;

    // ---- load x (3 floats, streaming) ----
    const float* xp = x + (size_t)i * 3;
    float xa = __builtin_nontemporal_load(xp + 0);
    float xb = __builtin_nontemporal_load(xp + 1);
    float xc = __builtin_nontemporal_load(xp + 2);

    // ---- bilinear sample (border padding, align_corners=False) ----
    float inp[8];
    {
        float gx = xa * 2.0f - 1.0f;
        float gy = xb * 2.0f - 1.0f;
        float ix = ((gx + 1.0f) * (float)W - 1.0f) * 0.5f;
        float iy = ((gy + 1.0f) * (float)H - 1.0f) * 0.5f;
        ix = fminf(fmaxf(ix, 0.0f), (float)(W - 1));
        iy = fminf(fmaxf(iy, 0.0f), (float)(H - 1));
        float x0f = floorf(ix), y0f = floorf(iy);
        float wx = ix - x0f, wy = iy - y0f;
        int x0 = (int)x0f, y0 = (int)y0f;
        int x1 = x0 + 1; if (x1 > W - 1) x1 = W - 1;
        int y1 = y0 + 1; if (y1 > H - 1) y1 = H - 1;

        float4 f00, f01, f10, f11;
        if (REPACKED) {
            f00 = fmr[y0 * W + x0];
            f01 = fmr[y0 * W + x1];
            f10 = fmr[y1 * W + x0];
            f11 = fmr[y1 * W + x1];
        } else {
            int HW = H * W;
            const float* c0 = fm;
            const float* c1 = fm + HW;
            const float* c2 = fm + 2 * HW;
            const float* c3 = fm + 3 * HW;
            int i00 = y0 * W + x0, i01 = y0 * W + x1;
            int i10 = y1 * W + x0, i11 = y1 * W + x1;
            f00 = make_float4(c0[i00], c1[i00], c2[i00], c3[i00]);
            f01 = make_float4(c0[i01], c1[i01], c2[i01], c3[i01]);
            f10 = make_float4(c0[i10], c1[i10], c2[i10], c3[i10]);
            f11 = make_float4(c0[i11], c1[i11], c2[i11], c3[i11]);
        }
        float omwx = 1.0f - wx, omwy = 1.0f - wy;
        float tx = f00.x * omwx + f01.x * wx, bx = f10.x * omwx + f11.x * wx;
        float ty = f00.y * omwx + f01.y * wx, by = f10.y * omwx + f11.y * wx;
        float tz = f00.z * omwx + f01.z * wx, bz = f10.z * omwx + f11.z * wx;
        float tw = f00.w * omwx + f01.w * wx, bw = f10.w * omwx + f11.w * wx;

        inp[0] = xa;
        inp[1] = xb;
        inp[2] = xc;
        inp[3] = tx * omwy + bx * wy;
        inp[4] = ty * omwy + by * wy;
        inp[5] = tz * omwy + bz * wy;
        inp[6] = tw * omwy + bw * wy;
        inp[7] = __expf(xc) - 1.0f;   // expm1, |x|<=1: no cancellation issue
    }

    // ---- layer 1: 8 -> 16, exact gelu ----
    float h1[16];
    #pragma unroll
    for (int j = 0; j < 16; ++j) {
        float acc = b1[j];
        #pragma unroll
        for (int k = 0; k < 8; ++k)
            acc = fmaf(W1[j * 8 + k], inp[k], acc);
        h1[j] = TABLE ? gelu_tbl(acc, gt) : gelu_as(acc);
    }

    // ---- layer 2: 16 -> 16 ----
    float h2[16];
    #pragma unroll
    for (int j = 0; j < 16; ++j) {
        float acc = b2[j];
        #pragma unroll
        for (int k = 0; k < 16; ++k)
            acc = fmaf(W2[j * 16 + k], h1[k], acc);
        h2[j] = TABLE ? gelu_tbl(acc, gt) : gelu_as(acc);
    }

    // ---- layer 3: 16 -> 16 ----
    float h3[16];
    #pragma unroll
    for (int j = 0; j < 16; ++j) {
        float acc = b3[j];
        #pragma unroll
        for (int k = 0; k < 16; ++k)
            acc = fmaf(W3[j * 16 + k], h2[k], acc);
        h3[j] = TABLE ? gelu_tbl(acc, gt) : gelu_as(acc);
    }

    // ---- head: 16 -> 3 + store (streaming) ----
    float* op = out + (size_t)i * 3;
    #pragma unroll
    for (int c = 0; c < 3; ++c) {
        float acc = bh[c];
        #pragma unroll
        for (int k = 0; k < 16; ++k)
            acc = fmaf(Wh[c * 16 + k], h3[k], acc);
        __builtin_nontemporal_store(acc, op + c);
    }
}

extern "C" void kernel_launch(void* const* d_in, const int* in_sizes, int n_in,
                              void* d_out, int out_size, void* d_ws, size_t ws_size,
                              hipStream_t stream) {
    const float* x  = (const float*)d_in[0];
    const float* fm = (const float*)d_in[1];
    const float* W1 = (const float*)d_in[2];
    const float* b1 = (const float*)d_in[3];
    const float* W2 = (const float*)d_in[4];
    const float* b2 = (const float*)d_in[5];
    const float* W3 = (const float*)d_in[6];
    const float* b3 = (const float*)d_in[7];
    const float* Wh = (const float*)d_in[8];
    const float* bh = (const float*)d_in[9];
    float* out = (float*)d_out;

    int B  = in_sizes[0] / 3;
    int HW = in_sizes[1] / 4;
    // assume square map (reference: 1024x1024)
    int H = 1;
    while ((long long)(H + 1) * (H + 1) <= (long long)HW) ++H;  // integer sqrt
    int W = HW / H;

    size_t repack_bytes = (size_t)HW * sizeof(float4);
    size_t table_bytes  = (size_t)GT_N * sizeof(float2);

    bool repack, table;
    float4* fmr = nullptr;
    float2* gtab = nullptr;
    if (ws_size >= repack_bytes + table_bytes) {
        repack = true; table = true;
        fmr = (float4*)d_ws;
        gtab = (float2*)((char*)d_ws + repack_bytes);
    } else if (ws_size >= repack_bytes) {
        repack = true; table = false;
        fmr = (float4*)d_ws;
    } else if (ws_size >= table_bytes) {
        repack = false; table = true;
        gtab = (float2*)d_ws;
    } else {
        repack = false; table = false;
    }

    if (repack) {
        int blocks = (HW + 255) / 256;
        repack_fm_kernel<<<blocks, 256, 0, stream>>>(fm, fmr, HW);
    }
    if (table) {
        build_gelu_table_kernel<<<GT_N / 256, 256, 0, stream>>>(gtab);
    }

    int blocks = (B + 255) / 256;
    if (repack && table) {
        fused_mlp_kernel<true, true><<<blocks, 256, 0, stream>>>(
            x, fm, fmr, gtab, W1, b1, W2, b2, W3, b3, Wh, bh, out, B, H, W);
    } else if (repack) {
        fused_mlp_kernel<true, false><<<blocks, 256, 0, stream>>>(
            x, fm, fmr, gtab, W1, b1, W2, b2, W3, b3, Wh, bh, out, B, H, W);
    } else if (table) {
        fused_mlp_kernel<false, true><<<blocks, 256, 0, stream>>>(
            x, fm, fmr, gtab, W1, b1, W2, b2, W3, b3, Wh, bh, out, B, H, W);
    } else {
        fused_mlp_kernel<false, false><<<blocks, 256, 0, stream>>>(
            x, fm, fmr, gtab, W1, b1, W2, b2, W3, b3, Wh, bh, out, B, H, W);
    }
}